// Round 1
// baseline (408.433 us; speedup 1.0000x reference)
//
#include <hip/hip_runtime.h>
#include <hip/hip_bf16.h>
#include <cstdint>
#include <cstddef>

#define BB 4
#define SEQ 2048
#define CD 768
#define NH 12
#define DH 64
#define MROWS (BB*SEQ)      // 8192
#define NQKV (3*CD)         // 2304

typedef float f32x4 __attribute__((ext_vector_type(4)));
typedef short bf16x8 __attribute__((ext_vector_type(8)));

static __device__ __forceinline__ unsigned short f2bf(float f) {
  union { float f; unsigned int u; } cv; cv.f = f;
  unsigned int u = cv.u;
  unsigned int r = (u + 0x7FFFu + ((u >> 16) & 1u)) >> 16;
  return (unsigned short)r;
}

#define GAS __attribute__((address_space(1)))
#define LAS __attribute__((address_space(3)))
static __device__ __forceinline__ void gl2lds16(const void* g, void* l) {
  __builtin_amdgcn_global_load_lds((const GAS void*)g, (LAS void*)l, 16, 0, 0);
}

#define MFMA(a, b, c) __builtin_amdgcn_mfma_f32_16x16x32_bf16((a), (b), (c), 0, 0, 0)

// ---------------- fp32 -> bf16 convert ----------------
__global__ __launch_bounds__(256) void cvt_bf16(const float* __restrict__ in,
                                                unsigned short* __restrict__ out, int n4) {
  int i = blockIdx.x * 256 + threadIdx.x;
  if (i >= n4) return;
  float4 v = reinterpret_cast<const float4*>(in)[i];
  unsigned int lo = (unsigned int)f2bf(v.x) | ((unsigned int)f2bf(v.y) << 16);
  unsigned int hi = (unsigned int)f2bf(v.z) | ((unsigned int)f2bf(v.w) << 16);
  reinterpret_cast<uint2*>(out)[i] = make_uint2(lo, hi);
}

// ---------------- QKV GEMM (128x128 tile) + fused bias + LN epilogue ----------------
// C[m, j] = sum_c Xb[m,c] * Wb[j,c] + bias[j]; j = t*768 + h*64 + d
// t==0 -> LN(q)*qg+qb -> Qo[b][h][n][d]; t==1 -> LN(k) -> Ko; t==2 -> raw -> Vo
__global__ __launch_bounds__(256) void qkv_gemm(
    const unsigned short* __restrict__ Xb, const unsigned short* __restrict__ Wb,
    const float* __restrict__ bias,
    const float* __restrict__ qg, const float* __restrict__ qbt,
    const float* __restrict__ kg, const float* __restrict__ kbt,
    unsigned short* __restrict__ Qo, unsigned short* __restrict__ Ko,
    unsigned short* __restrict__ Vo) {
  __shared__ unsigned short As[128 * 32];
  __shared__ unsigned short Bs[128 * 32];
  const int tid = threadIdx.x;
  const int wave = tid >> 6, lane = tid & 63;
  const int g = lane >> 4, cl = lane & 15;
  const int bm = blockIdx.x, bn = blockIdx.y;
  const int wr = (wave >> 1) * 64, wc = (wave & 1) * 64;

  f32x4 acc[4][4] = {};

  const int kc = (tid & 3) * 8;
  const unsigned short* ag0 = Xb + (size_t)(bm * 128 + (tid >> 2)) * CD + kc;
  const unsigned short* ag1 = ag0 + (size_t)64 * CD;
  const unsigned short* bg0 = Wb + (size_t)(bn * 128 + (tid >> 2)) * CD + kc;
  const unsigned short* bg1 = bg0 + (size_t)64 * CD;

  for (int k0 = 0; k0 < CD; k0 += 32) {
    gl2lds16(ag0 + k0, &As[tid * 8]);
    gl2lds16(ag1 + k0, &As[tid * 8 + 2048]);
    gl2lds16(bg0 + k0, &Bs[tid * 8]);
    gl2lds16(bg1 + k0, &Bs[tid * 8 + 2048]);
    __syncthreads();
    bf16x8 af[4], bfr[4];
#pragma unroll
    for (int i = 0; i < 4; ++i) af[i] = *(const bf16x8*)&As[(wr + i * 16 + cl) * 32 + g * 8];
#pragma unroll
    for (int j = 0; j < 4; ++j) bfr[j] = *(const bf16x8*)&Bs[(wc + j * 16 + cl) * 32 + g * 8];
#pragma unroll
    for (int i = 0; i < 4; ++i)
#pragma unroll
      for (int j = 0; j < 4; ++j) acc[i][j] = MFMA(af[i], bfr[j], acc[i][j]);
    __syncthreads();
  }

  // epilogue: this wave's 64 cols == one (t, h) block exactly
  const int j0 = bn * 128 + wc;
  const int t = j0 / CD;
  const int h = (j0 % CD) / DH;
  float bia[4], gam[4] = {0, 0, 0, 0}, bet[4] = {0, 0, 0, 0};
#pragma unroll
  for (int j = 0; j < 4; ++j) {
    int d = j * 16 + cl;
    bia[j] = bias[j0 + d];
    if (t == 0) { gam[j] = qg[d]; bet[j] = qbt[d]; }
    else if (t == 1) { gam[j] = kg[d]; bet[j] = kbt[d]; }
  }
  unsigned short* Out = (t == 0) ? Qo : (t == 1) ? Ko : Vo;
#pragma unroll
  for (int i = 0; i < 4; ++i) {
#pragma unroll
    for (int r = 0; r < 4; ++r) {
      float vj[4];
#pragma unroll
      for (int j = 0; j < 4; ++j) vj[j] = acc[i][j][r] + bia[j];
      const int m = bm * 128 + wr + i * 16 + g * 4 + r;
      const int b = m >> 11, n = m & 2047;
      size_t base = ((size_t)(b * NH + h) * SEQ + n) * DH;
      if (t < 2) {
        float s = vj[0] + vj[1] + vj[2] + vj[3];
        float ss = vj[0] * vj[0] + vj[1] * vj[1] + vj[2] * vj[2] + vj[3] * vj[3];
#pragma unroll
        for (int msk = 1; msk < 16; msk <<= 1) {
          s += __shfl_xor(s, msk, 64);
          ss += __shfl_xor(ss, msk, 64);
        }
        float mu = s * (1.0f / 64.0f);
        float var = ss * (1.0f / 64.0f) - mu * mu;
        float rstd = rsqrtf(var + 1e-5f);
#pragma unroll
        for (int j = 0; j < 4; ++j)
          Out[base + j * 16 + cl] = f2bf((vj[j] - mu) * rstd * gam[j] + bet[j]);
      } else {
#pragma unroll
        for (int j = 0; j < 4; ++j) Out[base + j * 16 + cl] = f2bf(vj[j]);
      }
    }
  }
}

// ---------------- Flash attention: 4 waves x 16 q rows, KBLK=32 ----------------
__global__ __launch_bounds__(256) void attn_fwd(
    const unsigned short* __restrict__ Qb, const unsigned short* __restrict__ Kb,
    const unsigned short* __restrict__ Vb, unsigned short* __restrict__ Ob) {
  __shared__ unsigned short kl[32 * 64];   // [key][d]
  __shared__ unsigned short vt[64 * 32];   // [d][key]
  __shared__ unsigned short pl[4][16 * 32];  // per-wave P [qrow][key]
  const int tid = threadIdx.x, wave = tid >> 6, lane = tid & 63;
  const int g = lane >> 4, cl = lane & 15;
  const int bh = blockIdx.y;
  const int q0 = blockIdx.x * 64;

  const unsigned short* qrow = Qb + ((size_t)bh * SEQ + q0 + wave * 16 + cl) * DH;
  const bf16x8 qf0 = *(const bf16x8*)&qrow[g * 8];
  const bf16x8 qf1 = *(const bf16x8*)&qrow[32 + g * 8];

  const unsigned short* Kh = Kb + (size_t)bh * SEQ * DH;
  const unsigned short* Vh = Vb + (size_t)bh * SEQ * DH;

  f32x4 oacc[4] = {};
  float mrow[4], lrow[4];
#pragma unroll
  for (int r = 0; r < 4; ++r) { mrow[r] = -__builtin_inff(); lrow[r] = 0.0f; }

  for (int kb0 = 0; kb0 < SEQ; kb0 += 32) {
    gl2lds16(&Kh[(size_t)(kb0 + (tid >> 3)) * DH + (tid & 7) * 8], &kl[tid * 8]);
    {
      const bf16x8 vv = *(const bf16x8*)&Vh[(size_t)(kb0 + (tid >> 3)) * DH + (tid & 7) * 8];
      const int key = tid >> 3, d0 = (tid & 7) * 8;
#pragma unroll
      for (int j = 0; j < 8; ++j) vt[(d0 + j) * 32 + key] = (unsigned short)vv[j];
    }
    __syncthreads();

    f32x4 s0 = {}, s1 = {};
    {
      bf16x8 k00 = *(const bf16x8*)&kl[cl * 64 + g * 8];
      bf16x8 k01 = *(const bf16x8*)&kl[cl * 64 + 32 + g * 8];
      bf16x8 k10 = *(const bf16x8*)&kl[(16 + cl) * 64 + g * 8];
      bf16x8 k11 = *(const bf16x8*)&kl[(16 + cl) * 64 + 32 + g * 8];
      s0 = MFMA(qf0, k00, s0);
      s0 = MFMA(qf1, k01, s0);
      s1 = MFMA(qf0, k10, s1);
      s1 = MFMA(qf1, k11, s1);
    }

    float pm[4], ps[4], corr[4];
#pragma unroll
    for (int r = 0; r < 4; ++r) {
      s0[r] *= 0.125f;
      s1[r] *= 0.125f;
      pm[r] = fmaxf(s0[r], s1[r]);
    }
#pragma unroll
    for (int msk = 1; msk < 16; msk <<= 1)
#pragma unroll
      for (int r = 0; r < 4; ++r) pm[r] = fmaxf(pm[r], __shfl_xor(pm[r], msk, 64));
#pragma unroll
    for (int r = 0; r < 4; ++r) {
      float mn = fmaxf(mrow[r], pm[r]);
      corr[r] = __expf(mrow[r] - mn);
      mrow[r] = mn;
      float p0 = __expf(s0[r] - mn);
      float p1 = __expf(s1[r] - mn);
      pl[wave][(g * 4 + r) * 32 + cl] = f2bf(p0);
      pl[wave][(g * 4 + r) * 32 + 16 + cl] = f2bf(p1);
      ps[r] = p0 + p1;
    }
#pragma unroll
    for (int msk = 1; msk < 16; msk <<= 1)
#pragma unroll
      for (int r = 0; r < 4; ++r) ps[r] += __shfl_xor(ps[r], msk, 64);
#pragma unroll
    for (int r = 0; r < 4; ++r) lrow[r] = lrow[r] * corr[r] + ps[r];
#pragma unroll
    for (int dt = 0; dt < 4; ++dt)
#pragma unroll
      for (int r = 0; r < 4; ++r) oacc[dt][r] *= corr[r];

    const bf16x8 pa = *(const bf16x8*)&pl[wave][cl * 32 + g * 8];
#pragma unroll
    for (int dt = 0; dt < 4; ++dt) {
      bf16x8 vf = *(const bf16x8*)&vt[(dt * 16 + cl) * 32 + g * 8];
      oacc[dt] = MFMA(pa, vf, oacc[dt]);
    }
    __syncthreads();
  }

  const int b = bh / NH, h = bh % NH;
#pragma unroll
  for (int r = 0; r < 4; ++r) {
    float inv = 1.0f / lrow[r];
    const int qr = q0 + wave * 16 + g * 4 + r;
    size_t base = ((size_t)(b * SEQ + qr)) * CD + h * DH;
#pragma unroll
    for (int dt = 0; dt < 4; ++dt) Ob[base + dt * 16 + cl] = f2bf(oacc[dt][r] * inv);
  }
}

// ---------------- Proj GEMM (128x128 tile) + bias, fp32 out ----------------
__global__ __launch_bounds__(256) void proj_gemm(
    const unsigned short* __restrict__ Ab, const unsigned short* __restrict__ Wb,
    const float* __restrict__ bias, float* __restrict__ out) {
  __shared__ unsigned short As[128 * 32];
  __shared__ unsigned short Bs[128 * 32];
  const int tid = threadIdx.x;
  const int wave = tid >> 6, lane = tid & 63;
  const int g = lane >> 4, cl = lane & 15;
  const int bm = blockIdx.x, bn = blockIdx.y;
  const int wr = (wave >> 1) * 64, wc = (wave & 1) * 64;

  f32x4 acc[4][4] = {};

  const int kc = (tid & 3) * 8;
  const unsigned short* ag0 = Ab + (size_t)(bm * 128 + (tid >> 2)) * CD + kc;
  const unsigned short* ag1 = ag0 + (size_t)64 * CD;
  const unsigned short* bg0 = Wb + (size_t)(bn * 128 + (tid >> 2)) * CD + kc;
  const unsigned short* bg1 = bg0 + (size_t)64 * CD;

  for (int k0 = 0; k0 < CD; k0 += 32) {
    gl2lds16(ag0 + k0, &As[tid * 8]);
    gl2lds16(ag1 + k0, &As[tid * 8 + 2048]);
    gl2lds16(bg0 + k0, &Bs[tid * 8]);
    gl2lds16(bg1 + k0, &Bs[tid * 8 + 2048]);
    __syncthreads();
    bf16x8 af[4], bfr[4];
#pragma unroll
    for (int i = 0; i < 4; ++i) af[i] = *(const bf16x8*)&As[(wr + i * 16 + cl) * 32 + g * 8];
#pragma unroll
    for (int j = 0; j < 4; ++j) bfr[j] = *(const bf16x8*)&Bs[(wc + j * 16 + cl) * 32 + g * 8];
#pragma unroll
    for (int i = 0; i < 4; ++i)
#pragma unroll
      for (int j = 0; j < 4; ++j) acc[i][j] = MFMA(af[i], bfr[j], acc[i][j]);
    __syncthreads();
  }

  const int j0 = bn * 128 + wc;
  float pb4[4];
#pragma unroll
  for (int j = 0; j < 4; ++j) pb4[j] = bias[j0 + j * 16 + cl];
#pragma unroll
  for (int i = 0; i < 4; ++i) {
#pragma unroll
    for (int r = 0; r < 4; ++r) {
      const int m = bm * 128 + wr + i * 16 + g * 4 + r;
      float* orow = out + (size_t)m * CD + j0;
#pragma unroll
      for (int j = 0; j < 4; ++j) orow[j * 16 + cl] = acc[i][j][r] + pb4[j];
    }
  }
}

extern "C" void kernel_launch(void* const* d_in, const int* in_sizes, int n_in,
                              void* d_out, int out_size, void* d_ws, size_t ws_size,
                              hipStream_t stream) {
  const float* x = (const float*)d_in[0];
  const float* qkv_w = (const float*)d_in[1];
  const float* qkv_b = (const float*)d_in[2];
  const float* proj_w = (const float*)d_in[3];
  const float* proj_b = (const float*)d_in[4];
  const float* q_gamma = (const float*)d_in[5];
  const float* q_beta = (const float*)d_in[6];
  const float* k_gamma = (const float*)d_in[7];
  const float* k_beta = (const float*)d_in[8];
  float* out = (float*)d_out;

  char* w = (char*)d_ws;
  unsigned short* Xb = (unsigned short*)w; w += (size_t)MROWS * CD * 2;
  unsigned short* Wq = (unsigned short*)w; w += (size_t)NQKV * CD * 2;
  unsigned short* Wp = (unsigned short*)w; w += (size_t)CD * CD * 2;
  unsigned short* Qo = (unsigned short*)w; w += (size_t)BB * NH * SEQ * DH * 2;
  unsigned short* Ko = (unsigned short*)w; w += (size_t)BB * NH * SEQ * DH * 2;
  unsigned short* Vo = (unsigned short*)w; w += (size_t)BB * NH * SEQ * DH * 2;
  unsigned short* Ob = (unsigned short*)w; w += (size_t)MROWS * CD * 2;

  cvt_bf16<<<MROWS * CD / 1024, 256, 0, stream>>>(x, Xb, MROWS * CD / 4);
  cvt_bf16<<<NQKV * CD / 1024, 256, 0, stream>>>(qkv_w, Wq, NQKV * CD / 4);
  cvt_bf16<<<CD * CD / 1024, 256, 0, stream>>>(proj_w, Wp, CD * CD / 4);

  qkv_gemm<<<dim3(MROWS / 128, NQKV / 128), 256, 0, stream>>>(
      Xb, Wq, qkv_b, q_gamma, q_beta, k_gamma, k_beta, Qo, Ko, Vo);

  attn_fwd<<<dim3(SEQ / 64, BB * NH), 256, 0, stream>>>(Qo, Ko, Vo, Ob);

  proj_gemm<<<dim3(MROWS / 128, CD / 128), 256, 0, stream>>>(Ob, Wp, proj_b, out);
}

// Round 2
// 254.737 us; speedup vs baseline: 1.6033x; 1.6033x over previous
//
#include <hip/hip_runtime.h>
#include <hip/hip_bf16.h>
#include <cstdint>
#include <cstddef>

#define BB 4
#define SEQ 2048
#define CD 768
#define NH 12
#define DH 64
#define MROWS (BB*SEQ)      // 8192
#define NQKV (3*CD)         // 2304

typedef float f32x4 __attribute__((ext_vector_type(4)));
typedef short bf16x8 __attribute__((ext_vector_type(8)));

static __device__ __forceinline__ unsigned short f2bf(float f) {
  union { float f; unsigned int u; } cv; cv.f = f;
  unsigned int u = cv.u;
  unsigned int r = (u + 0x7FFFu + ((u >> 16) & 1u)) >> 16;
  return (unsigned short)r;
}

#define GAS __attribute__((address_space(1)))
#define LAS __attribute__((address_space(3)))
static __device__ __forceinline__ void gl2lds16(const void* g, void* l) {
  __builtin_amdgcn_global_load_lds((const GAS void*)g, (LAS void*)l, 16, 0, 0);
}

#define MFMA(a, b, c) __builtin_amdgcn_mfma_f32_16x16x32_bf16((a), (b), (c), 0, 0, 0)

// ---------------- fp32 -> bf16 convert ----------------
__global__ __launch_bounds__(256) void cvt_bf16(const float* __restrict__ in,
                                                unsigned short* __restrict__ out, int n4) {
  int i = blockIdx.x * 256 + threadIdx.x;
  if (i >= n4) return;
  float4 v = reinterpret_cast<const float4*>(in)[i];
  unsigned int lo = (unsigned int)f2bf(v.x) | ((unsigned int)f2bf(v.y) << 16);
  unsigned int hi = (unsigned int)f2bf(v.z) | ((unsigned int)f2bf(v.w) << 16);
  reinterpret_cast<uint2*>(out)[i] = make_uint2(lo, hi);
}

// ---------------- QKV GEMM (128x128 tile) + fused bias + LN epilogue ----------------
__global__ __launch_bounds__(256) void qkv_gemm(
    const unsigned short* __restrict__ Xb, const unsigned short* __restrict__ Wb,
    const float* __restrict__ bias,
    const float* __restrict__ qg, const float* __restrict__ qbt,
    const float* __restrict__ kg, const float* __restrict__ kbt,
    unsigned short* __restrict__ Qo, unsigned short* __restrict__ Ko,
    unsigned short* __restrict__ Vo) {
  __shared__ unsigned short As[128 * 32];
  __shared__ unsigned short Bs[128 * 32];
  const int tid = threadIdx.x;
  const int wave = tid >> 6, lane = tid & 63;
  const int g = lane >> 4, cl = lane & 15;
  const int bm = blockIdx.x, bn = blockIdx.y;
  const int wr = (wave >> 1) * 64, wc = (wave & 1) * 64;

  f32x4 acc[4][4] = {};

  const int kc = (tid & 3) * 8;
  const unsigned short* ag0 = Xb + (size_t)(bm * 128 + (tid >> 2)) * CD + kc;
  const unsigned short* ag1 = ag0 + (size_t)64 * CD;
  const unsigned short* bg0 = Wb + (size_t)(bn * 128 + (tid >> 2)) * CD + kc;
  const unsigned short* bg1 = bg0 + (size_t)64 * CD;

  for (int k0 = 0; k0 < CD; k0 += 32) {
    gl2lds16(ag0 + k0, &As[tid * 8]);
    gl2lds16(ag1 + k0, &As[tid * 8 + 2048]);
    gl2lds16(bg0 + k0, &Bs[tid * 8]);
    gl2lds16(bg1 + k0, &Bs[tid * 8 + 2048]);
    __syncthreads();
    bf16x8 af[4], bfr[4];
#pragma unroll
    for (int i = 0; i < 4; ++i) af[i] = *(const bf16x8*)&As[(wr + i * 16 + cl) * 32 + g * 8];
#pragma unroll
    for (int j = 0; j < 4; ++j) bfr[j] = *(const bf16x8*)&Bs[(wc + j * 16 + cl) * 32 + g * 8];
#pragma unroll
    for (int i = 0; i < 4; ++i)
#pragma unroll
      for (int j = 0; j < 4; ++j) acc[i][j] = MFMA(af[i], bfr[j], acc[i][j]);
    __syncthreads();
  }

  const int j0 = bn * 128 + wc;
  const int t = j0 / CD;
  const int h = (j0 % CD) / DH;
  float bia[4], gam[4] = {0, 0, 0, 0}, bet[4] = {0, 0, 0, 0};
#pragma unroll
  for (int j = 0; j < 4; ++j) {
    int d = j * 16 + cl;
    bia[j] = bias[j0 + d];
    if (t == 0) { gam[j] = qg[d]; bet[j] = qbt[d]; }
    else if (t == 1) { gam[j] = kg[d]; bet[j] = kbt[d]; }
  }
  unsigned short* Out = (t == 0) ? Qo : (t == 1) ? Ko : Vo;
#pragma unroll
  for (int i = 0; i < 4; ++i) {
#pragma unroll
    for (int r = 0; r < 4; ++r) {
      float vj[4];
#pragma unroll
      for (int j = 0; j < 4; ++j) vj[j] = acc[i][j][r] + bia[j];
      const int m = bm * 128 + wr + i * 16 + g * 4 + r;
      const int b = m >> 11, n = m & 2047;
      size_t base = ((size_t)(b * NH + h) * SEQ + n) * DH;
      if (t < 2) {
        float s = vj[0] + vj[1] + vj[2] + vj[3];
        float ss = vj[0] * vj[0] + vj[1] * vj[1] + vj[2] * vj[2] + vj[3] * vj[3];
#pragma unroll
        for (int msk = 1; msk < 16; msk <<= 1) {
          s += __shfl_xor(s, msk, 64);
          ss += __shfl_xor(ss, msk, 64);
        }
        float mu = s * (1.0f / 64.0f);
        float var = ss * (1.0f / 64.0f) - mu * mu;
        float rstd = rsqrtf(var + 1e-5f);
#pragma unroll
        for (int j = 0; j < 4; ++j)
          Out[base + j * 16 + cl] = f2bf((vj[j] - mu) * rstd * gam[j] + bet[j]);
      } else {
#pragma unroll
        for (int j = 0; j < 4; ++j) Out[base + j * 16 + cl] = f2bf(vj[j]);
      }
    }
  }
}

// ---------------- V transpose: Vo[b,h,n,d] -> Vt[b,h,d,n] ----------------
__global__ __launch_bounds__(256) void transpose_v(const unsigned short* __restrict__ Vo,
                                                   unsigned short* __restrict__ Vt) {
  __shared__ unsigned short t[64 * 65];
  const int bh = blockIdx.y, n0 = blockIdx.x * 64;
  const int tid = threadIdx.x;
  const unsigned short* src = Vo + ((size_t)bh * SEQ + n0) * DH;
  const int r = tid >> 3, c0 = (tid & 7) * 8;
#pragma unroll
  for (int p = 0; p < 2; ++p) {
    bf16x8 v = *(const bf16x8*)&src[(size_t)(r + p * 32) * DH + c0];
#pragma unroll
    for (int j = 0; j < 8; ++j) t[(c0 + j) * 65 + (r + p * 32)] = (unsigned short)v[j];
  }
  __syncthreads();
  const int d = tid >> 2, nq = (tid & 3) * 16;
  unsigned short tmp[16];
#pragma unroll
  for (int j = 0; j < 16; ++j) tmp[j] = t[d * 65 + nq + j];
  unsigned short* dst = Vt + ((size_t)bh * DH + d) * SEQ + n0 + nq;
  *(bf16x8*)&dst[0] = *(const bf16x8*)&tmp[0];
  *(bf16x8*)&dst[8] = *(const bf16x8*)&tmp[8];
}

// ---------------- Flash attention: 4 waves x 16 q rows, KVBLK=64, swizzled LDS ----------------
__global__ __launch_bounds__(256) void attn_fwd(
    const unsigned short* __restrict__ Qb, const unsigned short* __restrict__ Kb,
    const unsigned short* __restrict__ Vtb, unsigned short* __restrict__ Ob) {
  __shared__ unsigned short kl[64 * 64];     // [key][d], rows 128B, XOR-swizzled
  __shared__ unsigned short vt[64 * 64];     // [d][key], rows 128B, XOR-swizzled
  __shared__ unsigned short pl[4][16 * 64];  // per-wave P [q][key], XOR-swizzled
  const int tid = threadIdx.x, wave = tid >> 6, lane = tid & 63;
  const int g = lane >> 4, cl = lane & 15;
  const int bh = blockIdx.y;
  const int q0 = blockIdx.x * 64;

  // Q A-frags (row = cl): contiguous 16B loads, hoisted
  const unsigned short* qrow = Qb + ((size_t)bh * SEQ + q0 + wave * 16 + cl) * DH;
  const bf16x8 qf0 = *(const bf16x8*)&qrow[g * 8];
  const bf16x8 qf1 = *(const bf16x8*)&qrow[32 + g * 8];

  const unsigned short* Kh = Kb + (size_t)bh * SEQ * DH;
  const unsigned short* Vth = Vtb + (size_t)bh * DH * SEQ;

  // staging: dest is linear tid*16B; pre-swizzle the global source column
  const int sr = tid >> 3;                       // row 0..31 (+32 on 2nd pass)
  const int sc = 8 * ((tid & 7) ^ (sr & 7));     // swizzled source column (shorts)

  f32x4 oacc[4] = {};
  float mrow[4], lrow[4];
#pragma unroll
  for (int r = 0; r < 4; ++r) { mrow[r] = -__builtin_inff(); lrow[r] = 0.0f; }

  for (int kb0 = 0; kb0 < SEQ; kb0 += 64) {
    gl2lds16(&Kh[(size_t)(kb0 + sr) * DH + sc], &kl[tid * 8]);
    gl2lds16(&Kh[(size_t)(kb0 + sr + 32) * DH + sc], &kl[tid * 8 + 2048]);
    gl2lds16(&Vth[(size_t)sr * SEQ + kb0 + sc], &vt[tid * 8]);
    gl2lds16(&Vth[(size_t)(sr + 32) * SEQ + kb0 + sc], &vt[tid * 8 + 2048]);
    __syncthreads();

    // QK^T: s[kt][r] = S[q = g*4+r][key = kt*16+cl]
    f32x4 s[4] = {};
#pragma unroll
    for (int kt = 0; kt < 4; ++kt) {
      const int krow = kt * 16 + cl;
      const int sw = (krow & 7) << 3;
      bf16x8 k0 = *(const bf16x8*)&kl[krow * 64 + ((g * 8) ^ sw)];
      bf16x8 k1 = *(const bf16x8*)&kl[krow * 64 + ((32 + g * 8) ^ sw)];
      s[kt] = MFMA(qf0, k0, s[kt]);
      s[kt] = MFMA(qf1, k1, s[kt]);
    }

    // online softmax over 64 keys
    float pm[4], ps[4], corr[4];
#pragma unroll
    for (int kt = 0; kt < 4; ++kt)
#pragma unroll
      for (int r = 0; r < 4; ++r) s[kt][r] *= 0.125f;
#pragma unroll
    for (int r = 0; r < 4; ++r)
      pm[r] = fmaxf(fmaxf(s[0][r], s[1][r]), fmaxf(s[2][r], s[3][r]));
#pragma unroll
    for (int msk = 1; msk < 16; msk <<= 1)
#pragma unroll
      for (int r = 0; r < 4; ++r) pm[r] = fmaxf(pm[r], __shfl_xor(pm[r], msk, 64));
#pragma unroll
    for (int r = 0; r < 4; ++r) {
      float mn = fmaxf(mrow[r], pm[r]);
      corr[r] = __expf(mrow[r] - mn);
      mrow[r] = mn;
      ps[r] = 0.0f;
    }
#pragma unroll
    for (int kt = 0; kt < 4; ++kt) {
#pragma unroll
      for (int r = 0; r < 4; ++r) {
        float p = __expf(s[kt][r] - mrow[r]);
        const int q = g * 4 + r;
        pl[wave][q * 64 + ((kt * 16 + cl) ^ ((q & 7) << 3))] = f2bf(p);
        ps[r] += p;
      }
    }
#pragma unroll
    for (int msk = 1; msk < 16; msk <<= 1)
#pragma unroll
      for (int r = 0; r < 4; ++r) ps[r] += __shfl_xor(ps[r], msk, 64);
#pragma unroll
    for (int r = 0; r < 4; ++r) lrow[r] = lrow[r] * corr[r] + ps[r];
#pragma unroll
    for (int dt = 0; dt < 4; ++dt)
#pragma unroll
      for (int r = 0; r < 4; ++r) oacc[dt][r] *= corr[r];

    // PV: O[q][d] += P[q][key] * V[key][d]
    const int swp = (cl & 7) << 3;
#pragma unroll
    for (int m = 0; m < 2; ++m) {
      bf16x8 pa = *(const bf16x8*)&pl[wave][cl * 64 + ((m * 32 + g * 8) ^ swp)];
#pragma unroll
      for (int dt = 0; dt < 4; ++dt) {
        const int vrow = dt * 16 + cl;
        bf16x8 vf = *(const bf16x8*)&vt[vrow * 64 + ((m * 32 + g * 8) ^ ((vrow & 7) << 3))];
        oacc[dt] = MFMA(pa, vf, oacc[dt]);
      }
    }
    __syncthreads();
  }

  const int b = bh / NH, h = bh % NH;
#pragma unroll
  for (int r = 0; r < 4; ++r) {
    float inv = 1.0f / lrow[r];
    const int qr = q0 + wave * 16 + g * 4 + r;
    size_t base = ((size_t)(b * SEQ + qr)) * CD + h * DH;
#pragma unroll
    for (int dt = 0; dt < 4; ++dt) Ob[base + dt * 16 + cl] = f2bf(oacc[dt][r] * inv);
  }
}

// ---------------- Proj GEMM (128x128 tile) + bias, fp32 out ----------------
__global__ __launch_bounds__(256) void proj_gemm(
    const unsigned short* __restrict__ Ab, const unsigned short* __restrict__ Wb,
    const float* __restrict__ bias, float* __restrict__ out) {
  __shared__ unsigned short As[128 * 32];
  __shared__ unsigned short Bs[128 * 32];
  const int tid = threadIdx.x;
  const int wave = tid >> 6, lane = tid & 63;
  const int g = lane >> 4, cl = lane & 15;
  const int bm = blockIdx.x, bn = blockIdx.y;
  const int wr = (wave >> 1) * 64, wc = (wave & 1) * 64;

  f32x4 acc[4][4] = {};

  const int kc = (tid & 3) * 8;
  const unsigned short* ag0 = Ab + (size_t)(bm * 128 + (tid >> 2)) * CD + kc;
  const unsigned short* ag1 = ag0 + (size_t)64 * CD;
  const unsigned short* bg0 = Wb + (size_t)(bn * 128 + (tid >> 2)) * CD + kc;
  const unsigned short* bg1 = bg0 + (size_t)64 * CD;

  for (int k0 = 0; k0 < CD; k0 += 32) {
    gl2lds16(ag0 + k0, &As[tid * 8]);
    gl2lds16(ag1 + k0, &As[tid * 8 + 2048]);
    gl2lds16(bg0 + k0, &Bs[tid * 8]);
    gl2lds16(bg1 + k0, &Bs[tid * 8 + 2048]);
    __syncthreads();
    bf16x8 af[4], bfr[4];
#pragma unroll
    for (int i = 0; i < 4; ++i) af[i] = *(const bf16x8*)&As[(wr + i * 16 + cl) * 32 + g * 8];
#pragma unroll
    for (int j = 0; j < 4; ++j) bfr[j] = *(const bf16x8*)&Bs[(wc + j * 16 + cl) * 32 + g * 8];
#pragma unroll
    for (int i = 0; i < 4; ++i)
#pragma unroll
      for (int j = 0; j < 4; ++j) acc[i][j] = MFMA(af[i], bfr[j], acc[i][j]);
    __syncthreads();
  }

  const int j0 = bn * 128 + wc;
  float pb4[4];
#pragma unroll
  for (int j = 0; j < 4; ++j) pb4[j] = bias[j0 + j * 16 + cl];
#pragma unroll
  for (int i = 0; i < 4; ++i) {
#pragma unroll
    for (int r = 0; r < 4; ++r) {
      const int m = bm * 128 + wr + i * 16 + g * 4 + r;
      float* orow = out + (size_t)m * CD + j0;
#pragma unroll
      for (int j = 0; j < 4; ++j) orow[j * 16 + cl] = acc[i][j][r] + pb4[j];
    }
  }
}

extern "C" void kernel_launch(void* const* d_in, const int* in_sizes, int n_in,
                              void* d_out, int out_size, void* d_ws, size_t ws_size,
                              hipStream_t stream) {
  const float* x = (const float*)d_in[0];
  const float* qkv_w = (const float*)d_in[1];
  const float* qkv_b = (const float*)d_in[2];
  const float* proj_w = (const float*)d_in[3];
  const float* proj_b = (const float*)d_in[4];
  const float* q_gamma = (const float*)d_in[5];
  const float* q_beta = (const float*)d_in[6];
  const float* k_gamma = (const float*)d_in[7];
  const float* k_beta = (const float*)d_in[8];
  float* out = (float*)d_out;

  char* w = (char*)d_ws;
  unsigned short* Xb = (unsigned short*)w; w += (size_t)MROWS * CD * 2;
  unsigned short* Wq = (unsigned short*)w; w += (size_t)NQKV * CD * 2;
  unsigned short* Wp = (unsigned short*)w; w += (size_t)CD * CD * 2;
  unsigned short* Qo = (unsigned short*)w; w += (size_t)BB * NH * SEQ * DH * 2;
  unsigned short* Ko = (unsigned short*)w; w += (size_t)BB * NH * SEQ * DH * 2;
  unsigned short* Vo = (unsigned short*)w; w += (size_t)BB * NH * SEQ * DH * 2;
  unsigned short* Ob = (unsigned short*)w; w += (size_t)MROWS * CD * 2;
  // Vt reuses the Xb region: Xb (12.58MB) is dead after qkv_gemm,
  // and BB*NH*DH*SEQ*2 == MROWS*CD*2 exactly.
  unsigned short* Vt = Xb;

  cvt_bf16<<<MROWS * CD / 1024, 256, 0, stream>>>(x, Xb, MROWS * CD / 4);
  cvt_bf16<<<NQKV * CD / 1024, 256, 0, stream>>>(qkv_w, Wq, NQKV * CD / 4);
  cvt_bf16<<<CD * CD / 1024, 256, 0, stream>>>(proj_w, Wp, CD * CD / 4);

  qkv_gemm<<<dim3(MROWS / 128, NQKV / 128), 256, 0, stream>>>(
      Xb, Wq, qkv_b, q_gamma, q_beta, k_gamma, k_beta, Qo, Ko, Vo);

  transpose_v<<<dim3(SEQ / 64, BB * NH), 256, 0, stream>>>(Vo, Vt);

  attn_fwd<<<dim3(SEQ / 64, BB * NH), 256, 0, stream>>>(Qo, Ko, Vt, Ob);

  proj_gemm<<<dim3(MROWS / 128, CD / 128), 256, 0, stream>>>(Ob, Wp, proj_b, out);
}

// Round 3
// 182.590 us; speedup vs baseline: 2.2369x; 1.3951x over previous
//
#include <hip/hip_runtime.h>
#include <hip/hip_bf16.h>
#include <cstdint>
#include <cstddef>

#define BB 4
#define SEQ 2048
#define CD 768
#define NH 12
#define DH 64
#define MROWS (BB*SEQ)      // 8192
#define NQKV (3*CD)         // 2304

typedef float f32x4 __attribute__((ext_vector_type(4)));
typedef float f32x16 __attribute__((ext_vector_type(16)));
typedef short bf16x8 __attribute__((ext_vector_type(8)));

static __device__ __forceinline__ unsigned short f2bf(float f) {
  union { float f; unsigned int u; } cv; cv.f = f;
  unsigned int u = cv.u;
  unsigned int r = (u + 0x7FFFu + ((u >> 16) & 1u)) >> 16;
  return (unsigned short)r;
}

#define GAS __attribute__((address_space(1)))
#define LAS __attribute__((address_space(3)))
static __device__ __forceinline__ void gl2lds16(const void* g, void* l) {
  __builtin_amdgcn_global_load_lds((const GAS void*)g, (LAS void*)l, 16, 0, 0);
}

#define MFMA(a, b, c) __builtin_amdgcn_mfma_f32_16x16x32_bf16((a), (b), (c), 0, 0, 0)
#define MFMA32(a, b, c) __builtin_amdgcn_mfma_f32_32x32x16_bf16((a), (b), (c), 0, 0, 0)
#define PACKBF(dst, x, y) asm("v_cvt_pk_bf16_f32 %0, %1, %2" : "=v"(dst) : "v"(x), "v"(y))

// 0.125 (1/sqrt(Dh)) * log2(e): folded into Q's gamma/beta so softmax uses exp2 directly
#define QSC 0.18033688011112042f

// ---------------- fp32 -> bf16 convert ----------------
__global__ __launch_bounds__(256) void cvt_bf16(const float* __restrict__ in,
                                                unsigned short* __restrict__ out, int n4) {
  int i = blockIdx.x * 256 + threadIdx.x;
  if (i >= n4) return;
  float4 v = reinterpret_cast<const float4*>(in)[i];
  unsigned int lo = (unsigned int)f2bf(v.x) | ((unsigned int)f2bf(v.y) << 16);
  unsigned int hi = (unsigned int)f2bf(v.z) | ((unsigned int)f2bf(v.w) << 16);
  reinterpret_cast<uint2*>(out)[i] = make_uint2(lo, hi);
}

// ---------------- QKV GEMM (128x128 tile) + fused bias + LN epilogue ----------------
__global__ __launch_bounds__(256) void qkv_gemm(
    const unsigned short* __restrict__ Xb, const unsigned short* __restrict__ Wb,
    const float* __restrict__ bias,
    const float* __restrict__ qg, const float* __restrict__ qbt,
    const float* __restrict__ kg, const float* __restrict__ kbt,
    unsigned short* __restrict__ Qo, unsigned short* __restrict__ Ko,
    unsigned short* __restrict__ Vo) {
  __shared__ unsigned short As[128 * 32];
  __shared__ unsigned short Bs[128 * 32];
  const int tid = threadIdx.x;
  const int wave = tid >> 6, lane = tid & 63;
  const int g = lane >> 4, cl = lane & 15;
  const int bm = blockIdx.x, bn = blockIdx.y;
  const int wr = (wave >> 1) * 64, wc = (wave & 1) * 64;

  f32x4 acc[4][4] = {};

  const int kc = (tid & 3) * 8;
  const unsigned short* ag0 = Xb + (size_t)(bm * 128 + (tid >> 2)) * CD + kc;
  const unsigned short* ag1 = ag0 + (size_t)64 * CD;
  const unsigned short* bg0 = Wb + (size_t)(bn * 128 + (tid >> 2)) * CD + kc;
  const unsigned short* bg1 = bg0 + (size_t)64 * CD;

  for (int k0 = 0; k0 < CD; k0 += 32) {
    gl2lds16(ag0 + k0, &As[tid * 8]);
    gl2lds16(ag1 + k0, &As[tid * 8 + 2048]);
    gl2lds16(bg0 + k0, &Bs[tid * 8]);
    gl2lds16(bg1 + k0, &Bs[tid * 8 + 2048]);
    __syncthreads();
    bf16x8 af[4], bfr[4];
#pragma unroll
    for (int i = 0; i < 4; ++i) af[i] = *(const bf16x8*)&As[(wr + i * 16 + cl) * 32 + g * 8];
#pragma unroll
    for (int j = 0; j < 4; ++j) bfr[j] = *(const bf16x8*)&Bs[(wc + j * 16 + cl) * 32 + g * 8];
#pragma unroll
    for (int i = 0; i < 4; ++i)
#pragma unroll
      for (int j = 0; j < 4; ++j) acc[i][j] = MFMA(af[i], bfr[j], acc[i][j]);
    __syncthreads();
  }

  const int j0 = bn * 128 + wc;
  const int t = j0 / CD;
  const int h = (j0 % CD) / DH;
  float bia[4], gam[4] = {0, 0, 0, 0}, bet[4] = {0, 0, 0, 0};
#pragma unroll
  for (int j = 0; j < 4; ++j) {
    int d = j * 16 + cl;
    bia[j] = bias[j0 + d];
    if (t == 0) { gam[j] = qg[d] * QSC; bet[j] = qbt[d] * QSC; }  // fold softmax scale into Q
    else if (t == 1) { gam[j] = kg[d]; bet[j] = kbt[d]; }
  }
  unsigned short* Out = (t == 0) ? Qo : (t == 1) ? Ko : Vo;
#pragma unroll
  for (int i = 0; i < 4; ++i) {
#pragma unroll
    for (int r = 0; r < 4; ++r) {
      float vj[4];
#pragma unroll
      for (int j = 0; j < 4; ++j) vj[j] = acc[i][j][r] + bia[j];
      const int m = bm * 128 + wr + i * 16 + g * 4 + r;
      const int b = m >> 11, n = m & 2047;
      size_t base = ((size_t)(b * NH + h) * SEQ + n) * DH;
      if (t < 2) {
        float s = vj[0] + vj[1] + vj[2] + vj[3];
        float ss = vj[0] * vj[0] + vj[1] * vj[1] + vj[2] * vj[2] + vj[3] * vj[3];
#pragma unroll
        for (int msk = 1; msk < 16; msk <<= 1) {
          s += __shfl_xor(s, msk, 64);
          ss += __shfl_xor(ss, msk, 64);
        }
        float mu = s * (1.0f / 64.0f);
        float var = ss * (1.0f / 64.0f) - mu * mu;
        float rstd = rsqrtf(var + 1e-5f);
#pragma unroll
        for (int j = 0; j < 4; ++j)
          Out[base + j * 16 + cl] = f2bf((vj[j] - mu) * rstd * gam[j] + bet[j]);
      } else {
#pragma unroll
        for (int j = 0; j < 4; ++j) Out[base + j * 16 + cl] = f2bf(vj[j]);
      }
    }
  }
}

// ---------------- V transpose: Vo[b,h,n,d] -> Vt[b,h,d,n] ----------------
__global__ __launch_bounds__(256) void transpose_v(const unsigned short* __restrict__ Vo,
                                                   unsigned short* __restrict__ Vt) {
  __shared__ unsigned short t[64 * 65];
  const int bh = blockIdx.y, n0 = blockIdx.x * 64;
  const int tid = threadIdx.x;
  const unsigned short* src = Vo + ((size_t)bh * SEQ + n0) * DH;
  const int r = tid >> 3, c0 = (tid & 7) * 8;
#pragma unroll
  for (int p = 0; p < 2; ++p) {
    bf16x8 v = *(const bf16x8*)&src[(size_t)(r + p * 32) * DH + c0];
#pragma unroll
    for (int j = 0; j < 8; ++j) t[(c0 + j) * 65 + (r + p * 32)] = (unsigned short)v[j];
  }
  __syncthreads();
  const int d = tid >> 2, nq = (tid & 3) * 16;
  unsigned short tmp[16];
#pragma unroll
  for (int j = 0; j < 16; ++j) tmp[j] = t[d * 65 + nq + j];
  unsigned short* dst = Vt + ((size_t)bh * DH + d) * SEQ + n0 + nq;
  *(bf16x8*)&dst[0] = *(const bf16x8*)&tmp[0];
  *(bf16x8*)&dst[8] = *(const bf16x8*)&tmp[8];
}

// ---------------- Flash attention: swapped QK^T, 32x32 MFMA, in-register softmax ----------------
// 4 waves x 32 q-rows, KVBLK=64. S^T = mfma(K, Q): lane holds S[key=crow(r,hi)+32ks][q=lane&31].
// crow(r,hi) = (r&3) + 8*(r>>2) + 4*hi  (verified m74/m101 C/D layout).
__global__ __launch_bounds__(256, 3) void attn_fwd(
    const unsigned short* __restrict__ Qb, const unsigned short* __restrict__ Kb,
    const unsigned short* __restrict__ Vtb, unsigned short* __restrict__ Ob) {
  __shared__ unsigned short kl[64 * 64];   // [key][d], 128B rows, XOR-swizzled
  __shared__ unsigned short vt[64 * 64];   // [d][key], 128B rows, XOR-swizzled
  __shared__ float linv[4][32];
  const int tid = threadIdx.x, wave = tid >> 6, lane = tid & 63;
  const int q32 = lane & 31, hi = lane >> 5;
  const int bh = blockIdx.y;
  const int qbase = blockIdx.x * 128 + wave * 32;

  // Q fragments (B-operand: row=q=lane&31, k = dc*16 + hi*8 + i), pre-scaled by QSC
  const unsigned short* qrow = Qb + ((size_t)bh * SEQ + qbase + q32) * DH + hi * 8;
  bf16x8 qf[4];
#pragma unroll
  for (int dc = 0; dc < 4; ++dc) qf[dc] = *(const bf16x8*)&qrow[dc * 16];

  const unsigned short* Kh = Kb + (size_t)bh * SEQ * DH;
  const unsigned short* Vth = Vtb + (size_t)bh * DH * SEQ;

  const int sr = tid >> 3;
  const int sc = 8 * ((tid & 7) ^ (sr & 7));
  const int ksw = (q32 & 7) << 3;   // swizzle term for rows q32 / q32+32 (same &7)

  f32x16 o0 = {}, o1 = {};
  float m = -__builtin_inff(), l = 0.0f;

  for (int kb0 = 0; kb0 < SEQ; kb0 += 64) {
    gl2lds16(&Kh[(size_t)(kb0 + sr) * DH + sc], &kl[tid * 8]);
    gl2lds16(&Kh[(size_t)(kb0 + sr + 32) * DH + sc], &kl[tid * 8 + 2048]);
    gl2lds16(&Vth[(size_t)sr * SEQ + kb0 + sc], &vt[tid * 8]);
    gl2lds16(&Vth[(size_t)(sr + 32) * SEQ + kb0 + sc], &vt[tid * 8 + 2048]);
    __syncthreads();

    // S^T = K . Q^T : A = K rows (key), B = Q rows (q)
    f32x16 s0 = {}, s1 = {};
#pragma unroll
    for (int dc = 0; dc < 4; ++dc) {
      const int colb = dc * 16 + hi * 8;
      bf16x8 kf0 = *(const bf16x8*)&kl[q32 * 64 + (colb ^ ksw)];
      bf16x8 kf1 = *(const bf16x8*)&kl[(32 + q32) * 64 + (colb ^ ksw)];
      s0 = MFMA32(kf0, qf[dc], s0);
      s1 = MFMA32(kf1, qf[dc], s1);
    }

    // online softmax, all in-register (lane owns q=lane&31's full 64-key row with lane^32)
    float vmax = s0[0];
#pragma unroll
    for (int r = 1; r < 16; ++r) vmax = fmaxf(vmax, s0[r]);
#pragma unroll
    for (int r = 0; r < 16; ++r) vmax = fmaxf(vmax, s1[r]);
    vmax = fmaxf(vmax, __shfl_xor(vmax, 32, 64));

    if (!__all(vmax - m <= 11.0f)) {   // defer-max (T13), log2 domain
      float mn = fmaxf(m, vmax);
      float corr = exp2f(m - mn);
      m = mn;
      l *= corr;
#pragma unroll
      for (int r = 0; r < 16; ++r) { o0[r] *= corr; o1[r] *= corr; }
    }

    float sum = 0.0f;
#pragma unroll
    for (int r = 0; r < 16; ++r) { s0[r] = exp2f(s0[r] - m); sum += s0[r]; }
#pragma unroll
    for (int r = 0; r < 16; ++r) { s1[r] = exp2f(s1[r] - m); sum += s1[r]; }
    sum += __shfl_xor(sum, 32, 64);
    l += sum;

    // P -> bf16 A-frags in-register (T12 exchange):
    // pa[c][i] = P[q][key = c*16 + 8*hi + i]
    bf16x8 pav[4];
#pragma unroll
    for (int c = 0; c < 4; ++c) {
      const int b = 8 * (c & 1);
      unsigned int wA0, wA1, wB0, wB1;
      if (c < 2) {
        PACKBF(wA0, s0[b + 0], s0[b + 1]); PACKBF(wA1, s0[b + 2], s0[b + 3]);
        PACKBF(wB0, s0[b + 4], s0[b + 5]); PACKBF(wB1, s0[b + 6], s0[b + 7]);
      } else {
        PACKBF(wA0, s1[b + 0], s1[b + 1]); PACKBF(wA1, s1[b + 2], s1[b + 3]);
        PACKBF(wB0, s1[b + 4], s1[b + 5]); PACKBF(wB1, s1[b + 6], s1[b + 7]);
      }
      unsigned int send0 = hi ? wA0 : wB0;
      unsigned int send1 = hi ? wA1 : wB1;
      unsigned int r0 = (unsigned int)__shfl_xor((int)send0, 32, 64);
      unsigned int r1 = (unsigned int)__shfl_xor((int)send1, 32, 64);
      union { unsigned int w[4]; bf16x8 v; } u;
      u.w[0] = hi ? r0 : wA0;
      u.w[1] = hi ? r1 : wA1;
      u.w[2] = hi ? wB0 : r0;
      u.w[3] = hi ? wB1 : r1;
      pav[c] = u.v;
    }

    // PV: O[q][d] += P[q][key] . V^T[d][key] ; B = V^T rows (d)
#pragma unroll
    for (int c = 0; c < 4; ++c) {
      const int colb = c * 16 + hi * 8;
      bf16x8 vf0 = *(const bf16x8*)&vt[q32 * 64 + (colb ^ ksw)];
      bf16x8 vf1 = *(const bf16x8*)&vt[(32 + q32) * 64 + (colb ^ ksw)];
      o0 = MFMA32(pav[c], vf0, o0);
      o1 = MFMA32(pav[c], vf1, o1);
    }
    __syncthreads();
  }

  linv[wave][q32] = 1.0f / l;   // hi-pair writes same value
  __syncthreads();
  const int b = bh / NH, h = bh % NH;
#pragma unroll
  for (int r = 0; r < 16; ++r) {
    const int qq = (r & 3) + 8 * (r >> 2) + 4 * hi;   // output row within 32
    float iv = linv[wave][qq];
    size_t base = ((size_t)(b * SEQ + qbase + qq)) * CD + h * DH;
    Ob[base + q32] = f2bf(o0[r] * iv);
    Ob[base + 32 + q32] = f2bf(o1[r] * iv);
  }
}

// ---------------- Proj GEMM (128x128 tile) + bias, fp32 out ----------------
__global__ __launch_bounds__(256) void proj_gemm(
    const unsigned short* __restrict__ Ab, const unsigned short* __restrict__ Wb,
    const float* __restrict__ bias, float* __restrict__ out) {
  __shared__ unsigned short As[128 * 32];
  __shared__ unsigned short Bs[128 * 32];
  const int tid = threadIdx.x;
  const int wave = tid >> 6, lane = tid & 63;
  const int g = lane >> 4, cl = lane & 15;
  const int bm = blockIdx.x, bn = blockIdx.y;
  const int wr = (wave >> 1) * 64, wc = (wave & 1) * 64;

  f32x4 acc[4][4] = {};

  const int kc = (tid & 3) * 8;
  const unsigned short* ag0 = Ab + (size_t)(bm * 128 + (tid >> 2)) * CD + kc;
  const unsigned short* ag1 = ag0 + (size_t)64 * CD;
  const unsigned short* bg0 = Wb + (size_t)(bn * 128 + (tid >> 2)) * CD + kc;
  const unsigned short* bg1 = bg0 + (size_t)64 * CD;

  for (int k0 = 0; k0 < CD; k0 += 32) {
    gl2lds16(ag0 + k0, &As[tid * 8]);
    gl2lds16(ag1 + k0, &As[tid * 8 + 2048]);
    gl2lds16(bg0 + k0, &Bs[tid * 8]);
    gl2lds16(bg1 + k0, &Bs[tid * 8 + 2048]);
    __syncthreads();
    bf16x8 af[4], bfr[4];
#pragma unroll
    for (int i = 0; i < 4; ++i) af[i] = *(const bf16x8*)&As[(wr + i * 16 + cl) * 32 + g * 8];
#pragma unroll
    for (int j = 0; j < 4; ++j) bfr[j] = *(const bf16x8*)&Bs[(wc + j * 16 + cl) * 32 + g * 8];
#pragma unroll
    for (int i = 0; i < 4; ++i)
#pragma unroll
      for (int j = 0; j < 4; ++j) acc[i][j] = MFMA(af[i], bfr[j], acc[i][j]);
    __syncthreads();
  }

  const int j0 = bn * 128 + wc;
  float pb4[4];
#pragma unroll
  for (int j = 0; j < 4; ++j) pb4[j] = bias[j0 + j * 16 + cl];
#pragma unroll
  for (int i = 0; i < 4; ++i) {
#pragma unroll
    for (int r = 0; r < 4; ++r) {
      const int m = bm * 128 + wr + i * 16 + g * 4 + r;
      float* orow = out + (size_t)m * CD + j0;
#pragma unroll
      for (int j = 0; j < 4; ++j) orow[j * 16 + cl] = acc[i][j][r] + pb4[j];
    }
  }
}

extern "C" void kernel_launch(void* const* d_in, const int* in_sizes, int n_in,
                              void* d_out, int out_size, void* d_ws, size_t ws_size,
                              hipStream_t stream) {
  const float* x = (const float*)d_in[0];
  const float* qkv_w = (const float*)d_in[1];
  const float* qkv_b = (const float*)d_in[2];
  const float* proj_w = (const float*)d_in[3];
  const float* proj_b = (const float*)d_in[4];
  const float* q_gamma = (const float*)d_in[5];
  const float* q_beta = (const float*)d_in[6];
  const float* k_gamma = (const float*)d_in[7];
  const float* k_beta = (const float*)d_in[8];
  float* out = (float*)d_out;

  char* w = (char*)d_ws;
  unsigned short* Xb = (unsigned short*)w; w += (size_t)MROWS * CD * 2;
  unsigned short* Wq = (unsigned short*)w; w += (size_t)NQKV * CD * 2;
  unsigned short* Wp = (unsigned short*)w; w += (size_t)CD * CD * 2;
  unsigned short* Qo = (unsigned short*)w; w += (size_t)BB * NH * SEQ * DH * 2;
  unsigned short* Ko = (unsigned short*)w; w += (size_t)BB * NH * SEQ * DH * 2;
  unsigned short* Vo = (unsigned short*)w; w += (size_t)BB * NH * SEQ * DH * 2;
  unsigned short* Ob = (unsigned short*)w; w += (size_t)MROWS * CD * 2;
  // Vt reuses the Xb region (dead after qkv_gemm); sizes match exactly.
  unsigned short* Vt = Xb;

  cvt_bf16<<<MROWS * CD / 1024, 256, 0, stream>>>(x, Xb, MROWS * CD / 4);
  cvt_bf16<<<NQKV * CD / 1024, 256, 0, stream>>>(qkv_w, Wq, NQKV * CD / 4);
  cvt_bf16<<<CD * CD / 1024, 256, 0, stream>>>(proj_w, Wp, CD * CD / 4);

  qkv_gemm<<<dim3(MROWS / 128, NQKV / 128), 256, 0, stream>>>(
      Xb, Wq, qkv_b, q_gamma, q_beta, k_gamma, k_beta, Qo, Ko, Vo);

  transpose_v<<<dim3(SEQ / 64, BB * NH), 256, 0, stream>>>(Vo, Vt);

  attn_fwd<<<dim3(SEQ / 128, BB * NH), 256, 0, stream>>>(Qo, Ko, Vt, Ob);

  proj_gemm<<<dim3(MROWS / 128, CD / 128), 256, 0, stream>>>(Ob, Wp, proj_b, out);
}